// Round 10
// baseline (92.224 us; speedup 1.0000x reference)
//
#include <hip/hip_runtime.h>
#include <math.h>

#define HH 2048
#define WW 2048

// Gaussian sigma=2, 5 taps, normalized
#define GW0 0.15246914402033867f
#define GW1 0.22184129554377693f
#define GW2 0.25137912086578894f

typedef float f4 __attribute__((ext_vector_type(4)));

#define NWI 4590            // interior waves: 9 strips x 510 row-groups (rows 4..2043, cols 4..2043)
#define NWB 144             // border waves: 16 top/bottom + 128 left/right
#define NACC (NWI + NWB)

struct R8 { float v[8]; };
struct R6 { float v[6]; };
struct Raw { f4 a, b, c; };

__device__ __forceinline__ R8 expand8(const f4& v) {
    R8 o;
    o.v[0] = __shfl_up(v.z, 1);  o.v[1] = __shfl_up(v.w, 1);
    o.v[2] = v.x; o.v[3] = v.y; o.v[4] = v.z; o.v[5] = v.w;
    o.v[6] = __shfl_down(v.x, 1); o.v[7] = __shfl_down(v.y, 1);
    return o;
}

// ============================ interior wave (shuffle-halo pipeline) ============================
__device__ __forceinline__ float interior_wave(const float* __restrict__ pred,
                                               const float* __restrict__ lab,
                                               int wid, int lane) {
    const int w  = wid % 9;
    const int rg = wid / 9;
    const int y0 = 4 + rg * 4;                 // outputs rows y0..y0+3 in [4,2043]
    const int cb = w * 248 + lane * 4;
    const int cbc = min(cb, WW - 4);
    const bool valid = (lane >= 1) && (lane <= 62) && (cb <= 2040);   // cols 4..2043

    const float T1f = 0.41421356237309503f;    // tan(pi/8)
    const float T3f = 2.41421356237309510f;    // tan(3pi/8)

    f4 hr[5];
    f4 blr[3];
    R8 er[5];
    R6 gxr[3], gyr[3];
    float lsum = 0.f;

    #pragma unroll
    for (int s = 0; s < 12; ++s) {
        // ---- h row y0-4+s (all rows real: y0-4 >= 0, y0+7 <= 2047) ----
        {
            const float* row = lab + (size_t)(y0 - 4 + s) * WW + cbc;
            f4 b = *(const f4*)row;
            float r0 = __shfl_up(b.z, 1), r1 = __shfl_up(b.w, 1);
            float r6 = __shfl_down(b.x, 1), r7 = __shfl_down(b.y, 1);
            f4 h;
            h.x = GW0 * (r0 + b.z) + GW1 * (r1 + b.y) + GW2 * b.x;
            h.y = GW0 * (r1 + b.w) + GW1 * (b.x + b.z) + GW2 * b.y;
            h.z = GW0 * (b.x + r6) + GW1 * (b.y + b.w) + GW2 * b.z;
            h.w = GW0 * (b.y + r7) + GW1 * (b.z + r6) + GW2 * b.w;
            hr[s % 5] = h;
        }

        if (s >= 4) {
            const int j = s - 4;               // blur + e row y0-2+j (real rows)
            blr[j % 3] = GW0 * (hr[j % 5] + hr[(j + 4) % 5]) +
                         GW1 * (hr[(j + 1) % 5] + hr[(j + 3) % 5]) +
                         GW2 * hr[(j + 2) % 5];
            const float* prow = pred + (size_t)(y0 - 2 + j) * WW + cbc;
            f4 p = *(const f4*)prow;
            f4 ex;
            ex.x = __expf(p.x * 10.f); ex.y = __expf(p.y * 10.f);
            ex.z = __expf(p.z * 10.f); ex.w = __expf(p.w * 10.f);
            er[j % 5] = expand8(ex);
        }

        if (s >= 6) {
            const int g = s - 6;               // gx/gy row y0-1+g
            R8 u = expand8(blr[g % 3]);
            R8 m = expand8(blr[(g + 1) % 3]);
            R8 d = expand8(blr[(g + 2) % 3]);
            float Sv[8], Dv[8];
            #pragma unroll
            for (int q = 0; q < 8; ++q) {
                Sv[q] = u.v[q] + 2.f * m.v[q] + d.v[q];
                Dv[q] = d.v[q] - u.v[q];
            }
            R6 gx6, gy6;
            #pragma unroll
            for (int q = 0; q < 6; ++q) {
                gx6.v[q] = (Sv[q + 2] - Sv[q]) * 0.125f;
                gy6.v[q] = (Dv[q] + 2.f * Dv[q + 1] + Dv[q + 2]) * 0.125f;
            }
            gxr[g % 3] = gx6; gyr[g % 3] = gy6;
        }

        if (s >= 8) {
            const int i = s - 8;               // output row y0+i
            const R6& X0 = gxr[i % 3];
            const R6& X1 = gxr[(i + 1) % 3];
            const R6& X2 = gxr[(i + 2) % 3];
            const R6& Y0 = gyr[i % 3];
            const R6& Y1 = gyr[(i + 1) % 3];
            const R6& Y2 = gyr[(i + 2) % 3];
            float Cx[6], Cy[6], Dy[6];
            #pragma unroll
            for (int q = 0; q < 6; ++q) {
                Cx[q] = X0.v[q] + 2.f * X1.v[q] + X2.v[q];
                Cy[q] = Y0.v[q] + 2.f * Y1.v[q] + Y2.v[q];
                Dy[q] = Y2.v[q] - Y0.v[q];
            }
            const R8& eA = er[i % 5];
            const R8& eB = er[(i + 1) % 5];
            const R8& eC = er[(i + 2) % 5];
            const R8& eD = er[(i + 3) % 5];
            const R8& eE = er[(i + 4) % 5];
            float P[8];
            P[0] = eC.v[0];
            #pragma unroll
            for (int q = 1; q < 8; ++q) P[q] = P[q - 1] + eC.v[q];

            #pragma unroll
            for (int k = 0; k < 4; ++k) {
                float gxx = (Cx[k + 2] - Cx[k]) * 0.125f;
                float gxy = (Cy[k + 2] - Cy[k]) * 0.125f;
                float gyy = (Dy[k] + 2.f * Dy[k + 1] + Dy[k + 2]) * 0.125f;

                float sg = -(gxy + 1e-6f);
                float sgn = (sg > 0.f) ? 1.f : ((sg < 0.f) ? -1.f : 0.f);
                float rt = gyy * sgn * __builtin_amdgcn_rcpf(gxx + 1e-6f);

                float hs  = (k == 0) ? P[4] : (P[k + 4] - P[k - 1]);
                float vs  = eA.v[k+2] + eB.v[k+2] + eC.v[k+2] + eD.v[k+2] + eE.v[k+2];
                float dls = eA.v[k]   + eB.v[k+1] + eC.v[k+2] + eD.v[k+3] + eE.v[k+4];
                float dcs = eA.v[k+4] + eB.v[k+3] + eC.v[k+2] + eD.v[k+1] + eE.v[k];

                bool isH = (rt >= -T1f) && (rt < T1f);
                bool isL = (rt >=  T1f) && (rt < T3f);
                bool isC = (rt >= -T3f) && (rt < -T1f);
                bool has = isH || isL || isC || (rt >= T3f) || (rt < -T3f);  // false only NaN
                float resp = isH ? hs : (isL ? dls : (isC ? dcs : vs));
                float lv = __logf(eC.v[k + 2]) - __logf(resp + 1e-6f);       // log(e)=pc*10
                lsum += (has && valid) ? lv : 0.f;
            }
        }
    }
    return lsum;
}

// ============================ border wave (R4/R8 staged path, proven) ============================
__device__ __forceinline__ int reflect_row(int vr) {
    return vr < 0 ? -vr : (vr >= HH ? 2 * HH - 2 - vr : vr);
}

__device__ __forceinline__ Raw load_row3(const float* __restrict__ p, int r, int xb) {
    const float* row = p + (size_t)r * WW;
    Raw o;
    o.a = *(const f4*)(row + max(xb - 4, 0));
    o.b = *(const f4*)(row + xb);
    o.c = *(const f4*)(row + min(xb + 4, WW - 4));
    return o;
}

__device__ __forceinline__ R8 make_h(const Raw& R, bool edgew, bool le, bool re) {
    float w[12] = {R.a.x, R.a.y, R.a.z, R.a.w, R.b.x, R.b.y, R.b.z, R.b.w,
                   R.c.x, R.c.y, R.c.z, R.c.w};
    if (edgew) {
        if (le) { w[0] = R.c.x; w[1] = R.b.w; w[2] = R.b.z; w[3] = R.b.y; }
        if (re) { w[8] = R.b.z; w[9] = R.b.y; w[10] = R.b.x; w[11] = R.a.w; }
    }
    R8 h;
    #pragma unroll
    for (int j = 0; j < 8; ++j)
        h.v[j] = GW0 * (w[j] + w[j + 4]) + GW1 * (w[j + 1] + w[j + 3]) + GW2 * w[j + 2];
    return h;
}

__device__ __forceinline__ R8 vg5(const R8& a, const R8& b, const R8& c, const R8& d, const R8& e_,
                                  bool edgew, bool le, bool re) {
    R8 o;
    #pragma unroll
    for (int j = 0; j < 8; ++j)
        o.v[j] = GW0 * (a.v[j] + e_.v[j]) + GW1 * (b.v[j] + d.v[j]) + GW2 * c.v[j];
    if (edgew) {
        if (le) { o.v[0] = o.v[2]; o.v[1] = o.v[2]; }
        if (re) { o.v[6] = o.v[5]; o.v[7] = o.v[5]; }
    }
    return o;
}

__device__ __forceinline__ void sobelB(const R8& u, const R8& m, const R8& d, R6& ox, R6& oy,
                                       bool edgew, bool le, bool re) {
    #pragma unroll
    for (int j = 0; j < 6; ++j) {
        ox.v[j] = ((u.v[j+2] - u.v[j]) + 2.f*(m.v[j+2] - m.v[j]) + (d.v[j+2] - d.v[j])) * 0.125f;
        oy.v[j] = ((d.v[j] - u.v[j]) + 2.f*(d.v[j+1] - u.v[j+1]) + (d.v[j+2] - u.v[j+2])) * 0.125f;
    }
    if (edgew) {
        if (le) { ox.v[0] = ox.v[1]; oy.v[0] = oy.v[1]; }
        if (re) { ox.v[5] = ox.v[4]; oy.v[5] = oy.v[4]; }
    }
}

__device__ __forceinline__ R8 erowB(const float* __restrict__ pred, int ry, int xb,
                                    bool edgew, bool le, bool re) {
    R8 o;
    if (ry < 0 || ry >= HH) {
        #pragma unroll
        for (int j = 0; j < 8; ++j) o.v[j] = 0.f;
        return o;
    }
    const float* row = pred + (size_t)ry * WW;
    f4 A = *(const f4*)(row + max(xb - 4, 0));
    f4 B = *(const f4*)(row + xb);
    f4 C = *(const f4*)(row + min(xb + 4, WW - 4));
    float w[8] = {A.z, A.w, B.x, B.y, B.z, B.w, C.x, C.y};
    #pragma unroll
    for (int j = 0; j < 8; ++j) o.v[j] = __expf(w[j] * 10.f);
    if (edgew) {
        if (le) { o.v[0] = 0.f; o.v[1] = 0.f; }
        if (re) { o.v[6] = 0.f; o.v[7] = 0.f; }
    }
    return o;
}

__device__ float border_wave(const float* __restrict__ pred, const float* __restrict__ lab,
                             int b, int lane) {
    int sx, y0, nt, laneMode;   // laneMode: 0=all lanes, 1=lane0 only, 2=lane63 only
    if (b < 16) { sx = b & 7; y0 = (b >> 3) ? 2044 : 0; nt = 4; laneMode = 0; }
    else {
        int j = b - 16; int side = j & 1; int g = j >> 1;
        y0 = 4 + 32 * g; nt = 32; sx = side ? 7 : 0; laneMode = side ? 2 : 1;
    }
    const int xb = sx * 256 + lane * 4;
    const bool edgew = (sx == 0) || (sx == 7);
    const bool le = (sx == 0) && (lane == 0);
    const bool re = (sx == 7) && (lane == 63);
    const bool lv = (laneMode == 0) || (laneMode == 1 && lane == 0) || (laneMode == 2 && lane == 63);

    const float T1f = 0.41421356237309503f;
    const float T3f = 2.41421356237309510f;

    R8 H0, H1, H2, H3, b0, b1;
    R6 gx0, gy0, gx1, gy1;
    {
        R8 A0 = make_h(load_row3(lab, reflect_row(y0 - 4), xb), edgew, le, re);
        R8 A1 = make_h(load_row3(lab, reflect_row(y0 - 3), xb), edgew, le, re);
        R8 A2 = make_h(load_row3(lab, reflect_row(y0 - 2), xb), edgew, le, re);
        R8 A3 = make_h(load_row3(lab, reflect_row(y0 - 1), xb), edgew, le, re);
        H0 = make_h(load_row3(lab, y0 + 0, xb), edgew, le, re);
        H1 = make_h(load_row3(lab, y0 + 1, xb), edgew, le, re);
        H2 = make_h(load_row3(lab, y0 + 2, xb), edgew, le, re);
        H3 = make_h(load_row3(lab, y0 + 3, xb), edgew, le, re);
        R8 bm2 = vg5(A0, A1, A2, A3, H0, edgew, le, re);
        R8 bm1 = vg5(A1, A2, A3, H0, H1, edgew, le, re);
        b0 = vg5(A2, A3, H0, H1, H2, edgew, le, re);
        b1 = vg5(A3, H0, H1, H2, H3, edgew, le, re);
        if (y0 > 0) {
            sobelB(bm2, bm1, b0, gx0, gy0, edgew, le, re);
            sobelB(bm1, b0,  b1, gx1, gy1, edgew, le, re);
        } else {
            sobelB(b0, b0, b1, gx1, gy1, edgew, le, re);
            gx0 = gx1; gy0 = gy1;
        }
    }

    R8 e0 = erowB(pred, y0 - 2, xb, edgew, le, re);
    R8 e1 = erowB(pred, y0 - 1, xb, edgew, le, re);
    R8 e2 = erowB(pred, y0 + 0, xb, edgew, le, re);
    R8 e3 = erowB(pred, y0 + 1, xb, edgew, le, re);

    float lsum = 0.f;

    for (int i = 0; i < nt; ++i) {
        const int y = y0 + i;

        R8 bn;
        if (y + 2 < HH) {
            R8 hn = make_h(load_row3(lab, reflect_row(y + 4), xb), edgew, le, re);
            bn = vg5(H0, H1, H2, H3, hn, edgew, le, re);
            H0 = H1; H1 = H2; H2 = H3; H3 = hn;
        } else bn = b1;

        R6 gxn, gyn;
        if (y + 1 < HH) sobelB(b0, b1, bn, gxn, gyn, edgew, le, re);
        else { gxn = gx1; gyn = gy1; }

        R8 en = erowB(pred, y + 2, xb, edgew, le, re);

        f4 pc4 = *(const f4*)(pred + (size_t)min(y, HH - 1) * WW + xb);
        float pcv[4] = {pc4.x, pc4.y, pc4.z, pc4.w};
        bool rowok = (laneMode == 0) || (y <= 2043);

        #pragma unroll
        for (int k = 0; k < 4; ++k) {
            float gxx = ((gx0.v[k+2]-gx0.v[k]) + 2.f*(gx1.v[k+2]-gx1.v[k]) +
                         (gxn.v[k+2]-gxn.v[k])) * 0.125f;
            float gxy = ((gy0.v[k+2]-gy0.v[k]) + 2.f*(gy1.v[k+2]-gy1.v[k]) +
                         (gyn.v[k+2]-gyn.v[k])) * 0.125f;
            float gyy = ((gyn.v[k]-gy0.v[k]) + 2.f*(gyn.v[k+1]-gy0.v[k+1]) +
                         (gyn.v[k+2]-gy0.v[k+2])) * 0.125f;
            float sg = -(gxy + 1e-6f);
            float sgn = (sg > 0.f) ? 1.f : ((sg < 0.f) ? -1.f : 0.f);
            float rt = gyy * sgn * __builtin_amdgcn_rcpf(gxx + 1e-6f);

            float hs  = e2.v[k] + e2.v[k+1] + e2.v[k+2] + e2.v[k+3] + e2.v[k+4];
            float vs  = e0.v[k+2] + e1.v[k+2] + e2.v[k+2] + e3.v[k+2] + en.v[k+2];
            float dls = e0.v[k]   + e1.v[k+1] + e2.v[k+2] + e3.v[k+3] + en.v[k+4];
            float dcs = e0.v[k+4] + e1.v[k+3] + e2.v[k+2] + e3.v[k+1] + en.v[k];

            bool isH = (rt >= -T1f) && (rt < T1f);
            bool isL = (rt >=  T1f) && (rt < T3f);
            bool isC = (rt >= -T3f) && (rt < -T1f);
            bool has = isH || isL || isC || (rt >= T3f) || (rt < -T3f);
            float resp = isH ? hs : (isL ? dls : (isC ? dcs : vs));
            float lvv = pcv[k] * 10.f - __logf(resp + 1e-6f);
            lsum += (has && lv && rowok) ? lvv : 0.f;
        }

        b0 = b1; b1 = bn;
        gx0 = gx1; gx1 = gxn; gy0 = gy1; gy1 = gyn;
        e0 = e1; e1 = e2; e2 = e3; e3 = en;
    }
    return lsum;
}

// ============================ main kernel ============================
__global__ __launch_bounds__(256) void steal_main(const float* __restrict__ pred,
                                                  const float* __restrict__ lab,
                                                  float* __restrict__ acc) {
    const int lane = threadIdx.x & 63;
    const int wid  = (blockIdx.x << 2) + (threadIdx.x >> 6);
    if (wid >= NACC) return;

    float lsum;
    if (wid < NWI) lsum = interior_wave(pred, lab, wid, lane);
    else           lsum = border_wave(pred, lab, wid - NWI, lane);

    #pragma unroll
    for (int off = 32; off; off >>= 1) lsum += __shfl_down(lsum, off, 64);
    if (lane == 0) acc[wid] = lsum;
}

__global__ __launch_bounds__(256) void steal_finalize(const float* __restrict__ acc,
                                                      float* __restrict__ out, int n) {
    __shared__ double sd[256];
    double a = 0.0;
    int n4 = n >> 2;
    for (int i = threadIdx.x; i < n4; i += 256) {
        f4 v = *(const f4*)(acc + i * 4);
        a += (double)v.x + (double)v.y + (double)v.z + (double)v.w;
    }
    for (int i = (n4 << 2) + threadIdx.x; i < n; i += 256) a += (double)acc[i];
    sd[threadIdx.x] = a;
    __syncthreads();
    for (int s = 128; s > 0; s >>= 1) {
        if (threadIdx.x < s) sd[threadIdx.x] += sd[threadIdx.x + s];
        __syncthreads();
    }
    if (threadIdx.x == 0) out[0] = (float)(-sd[0] / 4194304.0);
}

extern "C" void kernel_launch(void* const* d_in, const int* in_sizes, int n_in,
                              void* d_out, int out_size, void* d_ws, size_t ws_size,
                              hipStream_t stream) {
    const float* pred = (const float*)d_in[0];   // (1,1,2048,2048) f32
    const float* lab  = (const float*)d_in[1];   // (1,2048,2048) f32
    float* out = (float*)d_out;                  // scalar f32
    float* ws  = (float*)d_ws;

    const int nblocks = (NACC + 3) / 4;          // 1184 blocks x 256 threads
    steal_main<<<nblocks, 256, 0, stream>>>(pred, lab, ws);
    steal_finalize<<<1, 256, 0, stream>>>(ws, out, NACC);
}

// Round 11
// 35.106 us; speedup vs baseline: 2.6270x; 2.6270x over previous
//
#include <hip/hip_runtime.h>
#include <math.h>

#define HH 2048
#define WW 2048
#define T 8

// Gaussian sigma=2, 5 taps, normalized
#define GW0 0.15246914402033867f
#define GW1 0.22184129554377693f
#define GW2 0.25137912086578894f

typedef float f4 __attribute__((ext_vector_type(4)));

struct R8 { float v[8]; };
struct R6 { float v[6]; };
struct Raw { f4 a, b, c; };

__device__ __forceinline__ int reflect_row(int vr) {
    return vr < 0 ? -vr : (vr >= HH ? 2 * HH - 2 - vr : vr);
}

__device__ __forceinline__ Raw load_row3(const float* __restrict__ p, int r, int xb) {
    const float* row = p + (size_t)r * WW;
    Raw o;
    o.a = *(const f4*)(row + max(xb - 4, 0));
    o.b = *(const f4*)(row + xb);
    o.c = *(const f4*)(row + min(xb + 4, WW - 4));
    return o;
}

// horizontal gaussian from raw lab row; output covers x = xb-2 .. xb+5
__device__ __forceinline__ R8 make_h(const Raw& R, bool edgew, bool le, bool re) {
    float w[12] = {R.a.x, R.a.y, R.a.z, R.a.w, R.b.x, R.b.y, R.b.z, R.b.w,
                   R.c.x, R.c.y, R.c.z, R.c.w};
    if (edgew) {
        if (le) { w[0] = R.c.x; w[1] = R.b.w; w[2] = R.b.z; w[3] = R.b.y; }   // reflect left
        if (re) { w[8] = R.b.z; w[9] = R.b.y; w[10] = R.b.x; w[11] = R.a.w; } // reflect right
    }
    R8 h;
    #pragma unroll
    for (int j = 0; j < 8; ++j)
        h.v[j] = GW0 * (w[j] + w[j + 4]) + GW1 * (w[j + 1] + w[j + 3]) + GW2 * w[j + 2];
    return h;
}

// vertical gaussian -> blur row (8-wide), x-clamp fixups for sobel replicate pad
__device__ __forceinline__ R8 vg(const R8& a, const R8& b, const R8& c, const R8& d, const R8& e_,
                                 bool edgew, bool le, bool re) {
    R8 o;
    #pragma unroll
    for (int j = 0; j < 8; ++j)
        o.v[j] = GW0 * (a.v[j] + e_.v[j]) + GW1 * (b.v[j] + d.v[j]) + GW2 * c.v[j];
    if (edgew) {
        if (le) { o.v[0] = o.v[2]; o.v[1] = o.v[2]; }
        if (re) { o.v[6] = o.v[5]; o.v[7] = o.v[5]; }
    }
    return o;
}

// first sobel: 8-wide blur rows -> 6-wide gx,gy (x = xb-1 .. xb+4), x-clamp dup on edges
__device__ __forceinline__ void sobel(const R8& u, const R8& m, const R8& d, R6& ox, R6& oy,
                                      bool edgew, bool le, bool re) {
    #pragma unroll
    for (int j = 0; j < 6; ++j) {
        ox.v[j] = ((u.v[j+2] - u.v[j]) + 2.f*(m.v[j+2] - m.v[j]) + (d.v[j+2] - d.v[j])) * 0.125f;
        oy.v[j] = ((d.v[j] - u.v[j]) + 2.f*(d.v[j+1] - u.v[j+1]) + (d.v[j+2] - u.v[j+2])) * 0.125f;
    }
    if (edgew) {
        if (le) { ox.v[0] = ox.v[1]; oy.v[0] = oy.v[1]; }
        if (re) { ox.v[5] = ox.v[4]; oy.v[5] = oy.v[4]; }
    }
}

// exp row from a prefetched Raw; zrow -> zeros (row outside image); edge cols zeroed
__device__ __forceinline__ R8 erow_from(const Raw& R, bool zrow, bool edgew, bool le, bool re) {
    R8 o;
    if (zrow) {
        #pragma unroll
        for (int j = 0; j < 8; ++j) o.v[j] = 0.f;
        return o;
    }
    float w[8] = {R.a.z, R.a.w, R.b.x, R.b.y, R.b.z, R.b.w, R.c.x, R.c.y};
    #pragma unroll
    for (int j = 0; j < 8; ++j) o.v[j] = __expf(w[j] * 10.f);
    if (edgew) {
        if (le) { o.v[0] = 0.f; o.v[1] = 0.f; }
        if (re) { o.v[6] = 0.f; o.v[7] = 0.f; }
    }
    return o;
}

__global__ __launch_bounds__(256) void steal_main(const float* __restrict__ pred,
                                                  const float* __restrict__ lab,
                                                  float* __restrict__ acc) {
    __shared__ float s_red[4];
    const int lane = threadIdx.x & 63;
    const int wid  = (blockIdx.x << 2) + (threadIdx.x >> 6);   // 0..2047
    const int sx = wid & 7;
    const int y0 = (wid >> 3) * T;
    const int xb = sx * 256 + lane * 4;
    const bool edgew = (sx == 0) || (sx == 7);                 // wave-uniform
    const bool le = (sx == 0) && (lane == 0);
    const bool re = (sx == 7) && (lane == 63);

    const float T1f = 0.41421356237309503f;   // tan(pi/8)
    const float T3f = 2.41421356237309510f;   // tan(3pi/8)

    // ---------------- prime label pipeline ----------------
    R8 H0, H1, H2, H3, b0, b1;
    R6 gx0, gy0, gx1, gy1;
    {
        R8 A0 = make_h(load_row3(lab, reflect_row(y0 - 4), xb), edgew, le, re);
        R8 A1 = make_h(load_row3(lab, reflect_row(y0 - 3), xb), edgew, le, re);
        R8 A2 = make_h(load_row3(lab, reflect_row(y0 - 2), xb), edgew, le, re);
        R8 A3 = make_h(load_row3(lab, reflect_row(y0 - 1), xb), edgew, le, re);
        H0 = make_h(load_row3(lab, y0 + 0, xb), edgew, le, re);
        H1 = make_h(load_row3(lab, y0 + 1, xb), edgew, le, re);
        H2 = make_h(load_row3(lab, y0 + 2, xb), edgew, le, re);
        H3 = make_h(load_row3(lab, y0 + 3, xb), edgew, le, re);
        R8 bm2 = vg(A0, A1, A2, A3, H0, edgew, le, re);   // blur[y0-2]
        R8 bm1 = vg(A1, A2, A3, H0, H1, edgew, le, re);   // blur[y0-1]
        b0  = vg(A2, A3, H0, H1, H2, edgew, le, re);      // blur[y0]
        b1  = vg(A3, H0, H1, H2, H3, edgew, le, re);      // blur[y0+1]
        if (y0 > 0) {
            sobel(bm2, bm1, b0, gx0, gy0, edgew, le, re); // gxgy[y0-1]
            sobel(bm1, b0,  b1, gx1, gy1, edgew, le, re); // gxgy[y0]
        } else {
            sobel(b0, b0, b1, gx1, gy1, edgew, le, re);   // gxgy[0] (clamp dup)
            gx0 = gx1; gy0 = gy1;
        }
    }

    // ---------------- prime e window rows y0-2 .. y0+1 ----------------
    R8 e0 = erow_from(load_row3(pred, max(y0 - 2, 0), xb), (y0 - 2 < 0), edgew, le, re);
    R8 e1 = erow_from(load_row3(pred, max(y0 - 1, 0), xb), (y0 - 1 < 0), edgew, le, re);
    R8 e2 = erow_from(load_row3(pred, y0 + 0, xb), false, edgew, le, re);
    R8 e3 = erow_from(load_row3(pred, y0 + 1, xb), false, edgew, le, re);

    // ---------------- prefetch for iteration 0 (row y0): lab y0+4, pred y0+2, pc y0 ----
    Raw curLab  = load_row3(lab, reflect_row(y0 + 4), xb);
    Raw curPred = load_row3(pred, min(y0 + 2, HH - 1), xb);
    f4  curPc   = *(const f4*)(pred + (size_t)y0 * WW + xb);

    float lsum = 0.f;

    // ---------------- main loop: T output rows ----------------
    for (int i = 0; i < T; ++i) {
        const int y = y0 + i;

        // issue next iteration's loads first (consumed next iteration)
        Raw nLab  = load_row3(lab, reflect_row(y + 5), xb);
        Raw nPred = load_row3(pred, min(y + 3, HH - 1), xb);
        f4  nPc   = *(const f4*)(pred + (size_t)min(y + 1, HH - 1) * WW + xb);

        // ---- compute from current (already-resident) registers ----
        R8 bn;                                           // blur[y+2]
        if (y + 2 < HH) {
            R8 hn = make_h(curLab, edgew, le, re);
            bn = vg(H0, H1, H2, H3, hn, edgew, le, re);
            H0 = H1; H1 = H2; H2 = H3; H3 = hn;
        } else bn = b1;                                  // dup blur[H-1]

        R6 gxn, gyn;                                     // gxgy[y+1]
        if (y + 1 < HH) sobel(b0, b1, bn, gxn, gyn, edgew, le, re);
        else { gxn = gx1; gyn = gy1; }

        R8 en = erow_from(curPred, (y + 2 >= HH), edgew, le, re);   // e[y+2]

        float pcv[4] = {curPc.x, curPc.y, curPc.z, curPc.w};

        #pragma unroll
        for (int k = 0; k < 4; ++k) {
            float gxx = ((gx0.v[k+2]-gx0.v[k]) + 2.f*(gx1.v[k+2]-gx1.v[k]) +
                         (gxn.v[k+2]-gxn.v[k])) * 0.125f;
            float gxy = ((gy0.v[k+2]-gy0.v[k]) + 2.f*(gy1.v[k+2]-gy1.v[k]) +
                         (gyn.v[k+2]-gyn.v[k])) * 0.125f;
            float gyy = ((gyn.v[k]-gy0.v[k]) + 2.f*(gyn.v[k+1]-gy0.v[k+1]) +
                         (gyn.v[k+2]-gy0.v[k+2])) * 0.125f;
            float sg = -(gxy + 1e-6f);
            float sgn = (sg > 0.f) ? 1.f : ((sg < 0.f) ? -1.f : 0.f);
            float rt = gyy * sgn * __builtin_amdgcn_rcpf(gxx + 1e-6f);

            float hs  = e2.v[k] + e2.v[k+1] + e2.v[k+2] + e2.v[k+3] + e2.v[k+4];
            float vs  = e0.v[k+2] + e1.v[k+2] + e2.v[k+2] + e3.v[k+2] + en.v[k+2];
            float dls = e0.v[k]   + e1.v[k+1] + e2.v[k+2] + e3.v[k+3] + en.v[k+4];
            float dcs = e0.v[k+4] + e1.v[k+3] + e2.v[k+2] + e3.v[k+1] + en.v[k];

            bool isH = (rt >= -T1f) && (rt < T1f);
            bool isL = (rt >=  T1f) && (rt < T3f);
            bool isC = (rt >= -T3f) && (rt < -T1f);
            bool has = isH || isL || isC || (rt >= T3f) || (rt < -T3f);  // false only for NaN
            float resp = isH ? hs : (isL ? dls : (isC ? dcs : vs));
            float lv = pcv[k] * 10.f - __logf(resp + 1e-6f);
            lsum += has ? lv : 0.f;
        }

        // rotate windows + prefetch registers
        b0 = b1; b1 = bn;
        gx0 = gx1; gx1 = gxn; gy0 = gy1; gy1 = gyn;
        e0 = e1; e1 = e2; e2 = e3; e3 = en;
        curLab = nLab; curPred = nPred; curPc = nPc;
    }

    // ---------------- block reduction (wave = 64) ----------------
    float v = lsum;
    #pragma unroll
    for (int off = 32; off; off >>= 1) v += __shfl_down(v, off, 64);
    if ((threadIdx.x & 63) == 0) s_red[threadIdx.x >> 6] = v;
    __syncthreads();
    if (threadIdx.x == 0) {
        acc[blockIdx.x] = s_red[0] + s_red[1] + s_red[2] + s_red[3];
    }
}

__global__ __launch_bounds__(256) void steal_finalize(const float* __restrict__ acc,
                                                      float* __restrict__ out, int n) {
    __shared__ double sd[256];
    double a = 0.0;
    int n4 = n >> 2;
    for (int i = threadIdx.x; i < n4; i += 256) {
        f4 v = *(const f4*)(acc + i * 4);
        a += (double)v.x + (double)v.y + (double)v.z + (double)v.w;
    }
    for (int i = (n4 << 2) + threadIdx.x; i < n; i += 256) a += (double)acc[i];
    sd[threadIdx.x] = a;
    __syncthreads();
    for (int s = 128; s > 0; s >>= 1) {
        if (threadIdx.x < s) sd[threadIdx.x] += sd[threadIdx.x + s];
        __syncthreads();
    }
    if (threadIdx.x == 0) out[0] = (float)(-sd[0] / 4194304.0);
}

extern "C" void kernel_launch(void* const* d_in, const int* in_sizes, int n_in,
                              void* d_out, int out_size, void* d_ws, size_t ws_size,
                              hipStream_t stream) {
    const float* pred = (const float*)d_in[0];   // (1,1,2048,2048) f32
    const float* lab  = (const float*)d_in[1];   // (1,2048,2048) f32
    float* out = (float*)d_out;                  // scalar f32
    float* ws  = (float*)d_ws;

    const int nwaves = 8 * (HH / T);             // 2048 wave-jobs
    const int nblocks = nwaves / 4;              // 512 blocks x 256 threads

    steal_main<<<nblocks, 256, 0, stream>>>(pred, lab, ws);
    steal_finalize<<<1, 256, 0, stream>>>(ws, out, nblocks);
}